// Round 3
// baseline (700.464 us; speedup 1.0000x reference)
//
#include <hip/hip_runtime.h>
#include <cstdint>
#include <cstddef>

// Problem constants
#define Bb 8
#define Tt 2048
#define Cc 1024
#define Dd 1024
#define Mm (Bb*Tt)   // 16384 rows

// DTYPE NOTE (round 3): inputs/outputs are fp32 (as the reference declares).
// Evidence: round-2 (bf16-typed) produced NaN, which is impossible with true
// bf16 data (all values bounded -> no inf/0/0 anywhere even under indexing
// bugs) but guaranteed when fp32 mantissa bits land in bf16 exponent fields.
// Round-1 abort was d_ws overflow (344 MB); 160 MB ran clean. Keep ws <= 160 MB.

typedef __bf16  bf16x8  __attribute__((ext_vector_type(8)));
typedef float   floatx4 __attribute__((ext_vector_type(4)));

__device__ __forceinline__ ushort f2bf(float f) {
    unsigned u = __float_as_uint(f);
    u = (u + 0x7FFF + ((u >> 16) & 1)) >> 16;   // RNE
    return (ushort)u;
}
__device__ __forceinline__ float bf2f(ushort u) {
    return __uint_as_float(((unsigned)u) << 16);
}

__device__ __forceinline__ void load_lds16(const void* g, void* l) {
    __builtin_amdgcn_global_load_lds((__attribute__((address_space(1))) void*)(g),
                                     (__attribute__((address_space(3))) void*)(l),
                                     16, 0, 0);
}

// ---------------- mix + time-shift: fp32 x -> bf16 xm ----------------
// xm = x*w + xprev*(1-w); one projection per launch (xbuf reused serially).
__global__ __launch_bounds__(256) void prep_mix(
        const float* __restrict__ x, const float* __restrict__ w,
        ushort* __restrict__ xm) {
    int i  = blockIdx.x * 256 + threadIdx.x;     // vec8 chunk id, Mm*Cc/8 total
    int cq = i & (Cc / 8 - 1);                   // 128 vec8 per row
    int m  = i >> 7;
    int t  = m & (Tt - 1);
    float4 xc0 = ((const float4*)x)[i * 2];
    float4 xc1 = ((const float4*)x)[i * 2 + 1];
    float4 xp0 = make_float4(0.f, 0.f, 0.f, 0.f);
    float4 xp1 = xp0;
    if (t != 0) {
        xp0 = ((const float4*)x)[(i - Cc / 8) * 2];
        xp1 = ((const float4*)x)[(i - Cc / 8) * 2 + 1];
    }
    float4 w0 = ((const float4*)w)[cq * 2];
    float4 w1 = ((const float4*)w)[cq * 2 + 1];
    ushort o[8];
    o[0] = f2bf(xc0.x * w0.x + xp0.x * (1.f - w0.x));
    o[1] = f2bf(xc0.y * w0.y + xp0.y * (1.f - w0.y));
    o[2] = f2bf(xc0.z * w0.z + xp0.z * (1.f - w0.z));
    o[3] = f2bf(xc0.w * w0.w + xp0.w * (1.f - w0.w));
    o[4] = f2bf(xc1.x * w1.x + xp1.x * (1.f - w1.x));
    o[5] = f2bf(xc1.y * w1.y + xp1.y * (1.f - w1.y));
    o[6] = f2bf(xc1.z * w1.z + xp1.z * (1.f - w1.z));
    o[7] = f2bf(xc1.w * w1.w + xp1.w * (1.f - w1.w));
    ((ulonglong2*)xm)[i] = *(const ulonglong2*)o;
}

// ---------------- fp32 -> bf16 for the 4 weight matrices ----------------
__global__ __launch_bounds__(256) void cvt_w(
        const float* __restrict__ wk, const float* __restrict__ wv,
        const float* __restrict__ wr, const float* __restrict__ wo,
        ushort* __restrict__ ok, ushort* __restrict__ ov,
        ushort* __restrict__ orr, ushort* __restrict__ oo) {
    int i = blockIdx.x * 256 + threadIdx.x;       // vec4 units, 4 * 2^18 total
    int sel = i >> 18;
    int j = i & ((1 << 18) - 1);
    const float* s = sel == 0 ? wk : sel == 1 ? wv : sel == 2 ? wr : wo;
    ushort* d      = sel == 0 ? ok : sel == 1 ? ov : sel == 2 ? orr : oo;
    float4 f = ((const float4*)s)[j];
    ushort4 o;
    o.x = f2bf(f.x); o.y = f2bf(f.y); o.z = f2bf(f.z); o.w = f2bf(f.w);
    ((ushort4*)d)[j] = o;
}

// ---------------- NT GEMM: Co[m,n] = sum_k A[m,k] * Bw[n,k] ----------------
// A: M x K bf16 row-major, Bw: N x K bf16 row-major. 128x128 tile, BK=32.
// 4 waves, each 64x64 via 4x4 grid of 16x16x32 bf16 MFMAs (m97 structure).
// MODE: 0 = fp32 out, 1 = bf16 out, 2 = bf16 out + sigmoid, 3 = fp16 out
template<int MODE>
__global__ __launch_bounds__(256) void gemm_nt(
        const ushort* __restrict__ A, const ushort* __restrict__ Bw,
        void* __restrict__ Co, int Ndim, int Kdim) {
    __shared__ __attribute__((aligned(16))) __bf16 As[128 * 32];
    __shared__ __attribute__((aligned(16))) __bf16 Bs[128 * 32];
    const int tid  = threadIdx.x;
    const int lane = tid & 63;
    const int quad = lane >> 4;
    const int fr   = lane & 15;
    const int wave = tid >> 6;
    const int wm   = (wave >> 1) * 64;
    const int wn   = (wave & 1) * 64;
    const long tm  = (long)blockIdx.x * 128;
    const long tn  = (long)blockIdx.y * 128;

    // staging: thread t covers LDS bytes [t*16, t*16+16) = row t>>2, 16B part t&3
    const int srow  = tid >> 2;
    const int spart = tid & 3;
    const ushort* Ag0 = A + (tm + srow) * (long)Kdim + spart * 8;
    const ushort* Ag1 = Ag0 + 64 * (long)Kdim;
    const ushort* Bg0 = Bw + (tn + srow) * (long)Kdim + spart * 8;
    const ushort* Bg1 = Bg0 + 64 * (long)Kdim;
    // wave-uniform LDS bases: lane i deposits at base + i*16B
    __bf16* AlA = &As[wave * 512];
    __bf16* AlB = &As[2048 + wave * 512];
    __bf16* BlA = &Bs[wave * 512];
    __bf16* BlB = &Bs[2048 + wave * 512];

    floatx4 zero = {0.f, 0.f, 0.f, 0.f};
    floatx4 acc[4][4];
#pragma unroll
    for (int a1 = 0; a1 < 4; a1++)
#pragma unroll
        for (int b1 = 0; b1 < 4; b1++) acc[a1][b1] = zero;

    for (int kt = 0; kt < Kdim; kt += 32) {
        __syncthreads();                 // prior iter's LDS reads done
        load_lds16(Ag0 + kt, AlA);
        load_lds16(Ag1 + kt, AlB);
        load_lds16(Bg0 + kt, BlA);
        load_lds16(Bg1 + kt, BlB);
        __syncthreads();                 // staging drained (vmcnt0 before barrier)

        bf16x8 af[4], bfg[4];
#pragma unroll
        for (int mi = 0; mi < 4; mi++)
            af[mi] = *(const bf16x8*)&As[(wm + mi * 16 + fr) * 32 + quad * 8];
#pragma unroll
        for (int ni = 0; ni < 4; ni++)
            bfg[ni] = *(const bf16x8*)&Bs[(wn + ni * 16 + fr) * 32 + quad * 8];
#pragma unroll
        for (int mi = 0; mi < 4; mi++)
#pragma unroll
            for (int ni = 0; ni < 4; ni++)
                acc[mi][ni] = __builtin_amdgcn_mfma_f32_16x16x32_bf16(
                    af[mi], bfg[ni], acc[mi][ni], 0, 0, 0);
    }

#pragma unroll
    for (int mi = 0; mi < 4; mi++)
#pragma unroll
        for (int ni = 0; ni < 4; ni++)
#pragma unroll
            for (int r = 0; r < 4; r++) {
                long grow = tm + wm + mi * 16 + quad * 4 + r;
                long gcol = tn + wn + ni * 16 + fr;
                float v = acc[mi][ni][r];
                if (MODE == 2) v = 1.f / (1.f + __expf(-v));
                if (MODE == 0)      ((float*)Co)[grow * Ndim + gcol] = v;
                else if (MODE == 3) ((_Float16*)Co)[grow * Ndim + gcol] = (_Float16)v;
                else                ((ushort*)Co)[grow * Ndim + gcol] = f2bf(v);
            }
}

// ---------------- WKV sequential scan over T ----------------
// k fp16 (exp-sensitive), v/sr bf16, state fp32. 16-step register prefetch
// blocks: only 8192 chains = 128 waves exist, so per-step loads must be
// pipelined ~16 deep to amortize ~900-cyc HBM latency.
#define UU 16
__global__ __launch_bounds__(64) void wkv_scan(
        const _Float16* __restrict__ kb, const ushort* __restrict__ vb,
        const ushort* __restrict__ sr, const float* __restrict__ decay,
        const float* __restrict__ tf, ushort* __restrict__ rw) {
    int gid = blockIdx.x * 64 + threadIdx.x;   // 0..8191 = B*D
    int b = gid >> 10;
    int d = gid & 1023;
    float ew = __expf(-__expf(decay[d]));
    float eu = __expf(tf[d]);
    size_t base = ((size_t)b * Tt) * Dd + d;
    float a = 0.f, bs = 0.f;
    float kr[UU], vr[UU], rr[UU];
#pragma unroll
    for (int u = 0; u < UU; u++) {
        size_t idx = base + (size_t)u * Dd;
        kr[u] = (float)kb[idx]; vr[u] = bf2f(vb[idx]); rr[u] = bf2f(sr[idx]);
    }
    for (int t0 = 0; t0 < Tt; t0 += UU) {
        float k2[UU], v2[UU], r2[UU];
        if (t0 + UU < Tt) {
#pragma unroll
            for (int u = 0; u < UU; u++) {
                size_t idx = base + (size_t)(t0 + UU + u) * Dd;
                k2[u] = (float)kb[idx]; v2[u] = bf2f(vb[idx]); r2[u] = bf2f(sr[idx]);
            }
        } else {
#pragma unroll
            for (int u = 0; u < UU; u++) { k2[u] = 0.f; v2[u] = 0.f; r2[u] = 0.f; }
        }
#pragma unroll
        for (int u = 0; u < UU; u++) {
            float ek  = __expf(kr[u]);
            float ekv = ek * vr[u];
            float out = (eu * ekv + a) / (eu * ek + bs);
            a  = ew * a  + ekv;
            bs = ew * bs + ek;
            rw[base + (size_t)(t0 + u) * Dd] = f2bf(rr[u] * out);
        }
#pragma unroll
        for (int u = 0; u < UU; u++) { kr[u] = k2[u]; vr[u] = v2[u]; rr[u] = r2[u]; }
    }
}

extern "C" void kernel_launch(void* const* d_in, const int* in_sizes, int n_in,
                              void* d_out, int out_size, void* d_ws, size_t ws_size,
                              hipStream_t stream) {
    (void)in_sizes; (void)n_in; (void)out_size; (void)ws_size;
    const float* x  = (const float*)d_in[0];
    const float* td = (const float*)d_in[1];
    const float* tf = (const float*)d_in[2];
    const float* mk = (const float*)d_in[3];
    const float* mv = (const float*)d_in[4];
    const float* mr = (const float*)d_in[5];
    const float* Wk = (const float*)d_in[6];
    const float* Wv = (const float*)d_in[7];
    const float* Wr = (const float*)d_in[8];
    const float* Wo = (const float*)d_in[9];
    float* out = (float*)d_out;

    // workspace: 136 MB (xbuf reused for all 3 projections; rw aliases it)
    char* p = (char*)d_ws;
    auto take = [&](size_t n) { char* r = p; p += n; return r; };
    ushort*   xb = (ushort*)take((size_t)Mm * Cc * 2);     // 32 MB (also rw)
    _Float16* kb = (_Float16*)take((size_t)Mm * Dd * 2);   // 32 MB
    ushort*   vb = (ushort*)take((size_t)Mm * Dd * 2);     // 32 MB
    ushort*   sb = (ushort*)take((size_t)Mm * Dd * 2);     // 32 MB
    ushort*   wk = (ushort*)take((size_t)Dd * Cc * 2);     // 2 MB
    ushort*   wv = (ushort*)take((size_t)Dd * Cc * 2);
    ushort*   wr = (ushort*)take((size_t)Dd * Cc * 2);
    ushort*   wo = (ushort*)take((size_t)Cc * Dd * 2);
    ushort*   rw = xb;

    const int prep_grid = Mm * Cc / 8 / 256;
    dim3 g1(Mm / 128, Dd / 128);
    dim3 g2(Mm / 128, Cc / 128);

    cvt_w<<<4096, 256, 0, stream>>>(Wk, Wv, Wr, Wo, wk, wv, wr, wo);

    prep_mix<<<prep_grid, 256, 0, stream>>>(x, mk, xb);
    gemm_nt<3><<<g1, 256, 0, stream>>>(xb, wk, kb, Dd, Cc);

    prep_mix<<<prep_grid, 256, 0, stream>>>(x, mv, xb);
    gemm_nt<1><<<g1, 256, 0, stream>>>(xb, wv, vb, Dd, Cc);

    prep_mix<<<prep_grid, 256, 0, stream>>>(x, mr, xb);
    gemm_nt<2><<<g1, 256, 0, stream>>>(xb, wr, sb, Dd, Cc);

    wkv_scan<<<(Bb * Dd) / 64, 64, 0, stream>>>(kb, vb, sb, td, tf, rw);

    gemm_nt<0><<<g2, 256, 0, stream>>>(rw, wo, out, Cc, Dd);
}

// Round 4
// 443.561 us; speedup vs baseline: 1.5792x; 1.5792x over previous
//
#include <hip/hip_runtime.h>
#include <cstdint>
#include <cstddef>

// Problem constants
#define Bb 8
#define Tt 2048
#define Cc 1024
#define Dd 1024
#define Mm (Bb*Tt)   // 16384 rows
#define CL 64        // wkv chunk length
#define NCH (Tt/CL)  // 32 chunks

// DTYPE NOTE: inputs/outputs are fp32 (round-2 bf16 hypothesis disproved by
// NaN signature). Keep d_ws usage <= 160 MB (160 proven safe, 344 aborted).
// ROUND 4: wkv_scan was 318 us at 1.47% occupancy (128 waves, latency-bound).
// Replaced with 3-pass chunked parallel scan over the linear (a,b) recurrence.

typedef __bf16  bf16x8  __attribute__((ext_vector_type(8)));
typedef float   floatx4 __attribute__((ext_vector_type(4)));

__device__ __forceinline__ ushort f2bf(float f) {
    unsigned u = __float_as_uint(f);
    u = (u + 0x7FFF + ((u >> 16) & 1)) >> 16;   // RNE
    return (ushort)u;
}
__device__ __forceinline__ float bf2f(ushort u) {
    return __uint_as_float(((unsigned)u) << 16);
}

__device__ __forceinline__ void load_lds16(const void* g, void* l) {
    __builtin_amdgcn_global_load_lds((__attribute__((address_space(1))) void*)(g),
                                     (__attribute__((address_space(3))) void*)(l),
                                     16, 0, 0);
}

// ---------------- mix + time-shift: fp32 x -> bf16 xm ----------------
__global__ __launch_bounds__(256) void prep_mix(
        const float* __restrict__ x, const float* __restrict__ w,
        ushort* __restrict__ xm) {
    int i  = blockIdx.x * 256 + threadIdx.x;     // vec8 chunk id, Mm*Cc/8 total
    int cq = i & (Cc / 8 - 1);                   // 128 vec8 per row
    int m  = i >> 7;
    int t  = m & (Tt - 1);
    float4 xc0 = ((const float4*)x)[i * 2];
    float4 xc1 = ((const float4*)x)[i * 2 + 1];
    float4 xp0 = make_float4(0.f, 0.f, 0.f, 0.f);
    float4 xp1 = xp0;
    if (t != 0) {
        xp0 = ((const float4*)x)[(i - Cc / 8) * 2];
        xp1 = ((const float4*)x)[(i - Cc / 8) * 2 + 1];
    }
    float4 w0 = ((const float4*)w)[cq * 2];
    float4 w1 = ((const float4*)w)[cq * 2 + 1];
    ushort o[8];
    o[0] = f2bf(xc0.x * w0.x + xp0.x * (1.f - w0.x));
    o[1] = f2bf(xc0.y * w0.y + xp0.y * (1.f - w0.y));
    o[2] = f2bf(xc0.z * w0.z + xp0.z * (1.f - w0.z));
    o[3] = f2bf(xc0.w * w0.w + xp0.w * (1.f - w0.w));
    o[4] = f2bf(xc1.x * w1.x + xp1.x * (1.f - w1.x));
    o[5] = f2bf(xc1.y * w1.y + xp1.y * (1.f - w1.y));
    o[6] = f2bf(xc1.z * w1.z + xp1.z * (1.f - w1.z));
    o[7] = f2bf(xc1.w * w1.w + xp1.w * (1.f - w1.w));
    ((ulonglong2*)xm)[i] = *(const ulonglong2*)o;
}

// ---------------- fp32 -> bf16 for the 4 weight matrices ----------------
__global__ __launch_bounds__(256) void cvt_w(
        const float* __restrict__ wk, const float* __restrict__ wv,
        const float* __restrict__ wr, const float* __restrict__ wo,
        ushort* __restrict__ ok, ushort* __restrict__ ov,
        ushort* __restrict__ orr, ushort* __restrict__ oo) {
    int i = blockIdx.x * 256 + threadIdx.x;       // vec4 units, 4 * 2^18 total
    int sel = i >> 18;
    int j = i & ((1 << 18) - 1);
    const float* s = sel == 0 ? wk : sel == 1 ? wv : sel == 2 ? wr : wo;
    ushort* d      = sel == 0 ? ok : sel == 1 ? ov : sel == 2 ? orr : oo;
    float4 f = ((const float4*)s)[j];
    ushort4 o;
    o.x = f2bf(f.x); o.y = f2bf(f.y); o.z = f2bf(f.z); o.w = f2bf(f.w);
    ((ushort4*)d)[j] = o;
}

// ---------------- NT GEMM: Co[m,n] = sum_k A[m,k] * Bw[n,k] ----------------
// MODE: 0 = fp32 out, 1 = bf16 out, 2 = bf16 out + sigmoid, 3 = fp16 out
template<int MODE>
__global__ __launch_bounds__(256) void gemm_nt(
        const ushort* __restrict__ A, const ushort* __restrict__ Bw,
        void* __restrict__ Co, int Ndim, int Kdim) {
    __shared__ __attribute__((aligned(16))) __bf16 As[128 * 32];
    __shared__ __attribute__((aligned(16))) __bf16 Bs[128 * 32];
    const int tid  = threadIdx.x;
    const int lane = tid & 63;
    const int quad = lane >> 4;
    const int fr   = lane & 15;
    const int wave = tid >> 6;
    const int wm   = (wave >> 1) * 64;
    const int wn   = (wave & 1) * 64;
    const long tm  = (long)blockIdx.x * 128;
    const long tn  = (long)blockIdx.y * 128;

    const int srow  = tid >> 2;
    const int spart = tid & 3;
    const ushort* Ag0 = A + (tm + srow) * (long)Kdim + spart * 8;
    const ushort* Ag1 = Ag0 + 64 * (long)Kdim;
    const ushort* Bg0 = Bw + (tn + srow) * (long)Kdim + spart * 8;
    const ushort* Bg1 = Bg0 + 64 * (long)Kdim;
    __bf16* AlA = &As[wave * 512];
    __bf16* AlB = &As[2048 + wave * 512];
    __bf16* BlA = &Bs[wave * 512];
    __bf16* BlB = &Bs[2048 + wave * 512];

    floatx4 zero = {0.f, 0.f, 0.f, 0.f};
    floatx4 acc[4][4];
#pragma unroll
    for (int a1 = 0; a1 < 4; a1++)
#pragma unroll
        for (int b1 = 0; b1 < 4; b1++) acc[a1][b1] = zero;

    for (int kt = 0; kt < Kdim; kt += 32) {
        __syncthreads();
        load_lds16(Ag0 + kt, AlA);
        load_lds16(Ag1 + kt, AlB);
        load_lds16(Bg0 + kt, BlA);
        load_lds16(Bg1 + kt, BlB);
        __syncthreads();

        bf16x8 af[4], bfg[4];
#pragma unroll
        for (int mi = 0; mi < 4; mi++)
            af[mi] = *(const bf16x8*)&As[(wm + mi * 16 + fr) * 32 + quad * 8];
#pragma unroll
        for (int ni = 0; ni < 4; ni++)
            bfg[ni] = *(const bf16x8*)&Bs[(wn + ni * 16 + fr) * 32 + quad * 8];
#pragma unroll
        for (int mi = 0; mi < 4; mi++)
#pragma unroll
            for (int ni = 0; ni < 4; ni++)
                acc[mi][ni] = __builtin_amdgcn_mfma_f32_16x16x32_bf16(
                    af[mi], bfg[ni], acc[mi][ni], 0, 0, 0);
    }

#pragma unroll
    for (int mi = 0; mi < 4; mi++)
#pragma unroll
        for (int ni = 0; ni < 4; ni++)
#pragma unroll
            for (int r = 0; r < 4; r++) {
                long grow = tm + wm + mi * 16 + quad * 4 + r;
                long gcol = tn + wn + ni * 16 + fr;
                float v = acc[mi][ni][r];
                if (MODE == 2) v = 1.f / (1.f + __expf(-v));
                if (MODE == 0)      ((float*)Co)[grow * Ndim + gcol] = v;
                else if (MODE == 3) ((_Float16*)Co)[grow * Ndim + gcol] = (_Float16)v;
                else                ((ushort*)Co)[grow * Ndim + gcol] = f2bf(v);
            }
}

// ---------------- WKV: 3-pass chunked parallel scan ----------------
// Pass 1: per-(b,chunk,d) local scan with zero init -> partial (a,b) state.
__global__ __launch_bounds__(256) void wkv_part(
        const _Float16* __restrict__ kb, const ushort* __restrict__ vb,
        const float* __restrict__ decay,
        float* __restrict__ pa, float* __restrict__ pb) {
    int gid = blockIdx.x * 256 + threadIdx.x;   // 0..B*NCH*D-1, d fastest
    int d = gid & (Dd - 1);
    int c = (gid >> 10) & (NCH - 1);
    int b = gid >> 15;
    float ew = __expf(-__expf(decay[d]));
    size_t base = ((size_t)b * Tt + (size_t)c * CL) * Dd + d;
    float a = 0.f, bs = 0.f;
    for (int i0 = 0; i0 < CL; i0 += 8) {
        float kr[8], vr[8];
#pragma unroll
        for (int j = 0; j < 8; j++) {
            size_t idx = base + (size_t)(i0 + j) * Dd;
            kr[j] = (float)kb[idx]; vr[j] = bf2f(vb[idx]);
        }
#pragma unroll
        for (int j = 0; j < 8; j++) {
            float ek = __expf(kr[j]);
            a  = ew * a  + ek * vr[j];
            bs = ew * bs + ek;
        }
    }
    int sidx = c * (Bb * Dd) + b * Dd + d;      // [c][b][d]
    pa[sidx] = a; pb[sidx] = bs;
}

// Pass 2: per-(b,d) serial combine of 32 chunk partials -> chunk init states.
__global__ __launch_bounds__(256) void wkv_prefix(
        const float* __restrict__ pa, const float* __restrict__ pb,
        const float* __restrict__ decay,
        float* __restrict__ sa, float* __restrict__ sb) {
    int gid = blockIdx.x * 256 + threadIdx.x;   // 0..B*D-1
    int d = gid & (Dd - 1);
    float ewL = __expf(-__expf(decay[d]) * (float)CL);  // ew^CL, direct
    float ca = 0.f, cb = 0.f;
#pragma unroll
    for (int c = 0; c < NCH; c++) {
        int idx = c * (Bb * Dd) + gid;
        sa[idx] = ca; sb[idx] = cb;
        ca = ewL * ca + pa[idx];
        cb = ewL * cb + pb[idx];
    }
}

// Pass 3: per-(b,chunk,d) replay with correct init; emit rw = sr * wkv (bf16).
__global__ __launch_bounds__(256) void wkv_chunk(
        const _Float16* __restrict__ kb, const ushort* __restrict__ vb,
        const ushort* __restrict__ sr,
        const float* __restrict__ decay, const float* __restrict__ tf,
        const float* __restrict__ sa, const float* __restrict__ sb,
        ushort* __restrict__ rw) {
    int gid = blockIdx.x * 256 + threadIdx.x;
    int d = gid & (Dd - 1);
    int c = (gid >> 10) & (NCH - 1);
    int b = gid >> 15;
    float ew = __expf(-__expf(decay[d]));
    float eu = __expf(tf[d]);
    int sidx = c * (Bb * Dd) + b * Dd + d;
    float a = sa[sidx], bs = sb[sidx];
    size_t base = ((size_t)b * Tt + (size_t)c * CL) * Dd + d;
    for (int i0 = 0; i0 < CL; i0 += 8) {
        float kr[8], vr[8], rr[8];
#pragma unroll
        for (int j = 0; j < 8; j++) {
            size_t idx = base + (size_t)(i0 + j) * Dd;
            kr[j] = (float)kb[idx]; vr[j] = bf2f(vb[idx]); rr[j] = bf2f(sr[idx]);
        }
#pragma unroll
        for (int j = 0; j < 8; j++) {
            float ek  = __expf(kr[j]);
            float ekv = ek * vr[j];
            float out = (eu * ekv + a) / (eu * ek + bs);
            a  = ew * a  + ekv;
            bs = ew * bs + ek;
            rw[base + (size_t)(i0 + j) * Dd] = f2bf(rr[j] * out);
        }
    }
}

extern "C" void kernel_launch(void* const* d_in, const int* in_sizes, int n_in,
                              void* d_out, int out_size, void* d_ws, size_t ws_size,
                              hipStream_t stream) {
    (void)in_sizes; (void)n_in; (void)out_size; (void)ws_size;
    const float* x  = (const float*)d_in[0];
    const float* td = (const float*)d_in[1];
    const float* tf = (const float*)d_in[2];
    const float* mk = (const float*)d_in[3];
    const float* mv = (const float*)d_in[4];
    const float* mr = (const float*)d_in[5];
    const float* Wk = (const float*)d_in[6];
    const float* Wv = (const float*)d_in[7];
    const float* Wr = (const float*)d_in[8];
    const float* Wo = (const float*)d_in[9];
    float* out = (float*)d_out;

    // workspace: 140 MB
    char* p = (char*)d_ws;
    auto take = [&](size_t n) { char* r = p; p += n; return r; };
    ushort*   xb = (ushort*)take((size_t)Mm * Cc * 2);     // 32 MB (also rw)
    _Float16* kb = (_Float16*)take((size_t)Mm * Dd * 2);   // 32 MB
    ushort*   vb = (ushort*)take((size_t)Mm * Dd * 2);     // 32 MB
    ushort*   sb = (ushort*)take((size_t)Mm * Dd * 2);     // 32 MB
    ushort*   wk = (ushort*)take((size_t)Dd * Cc * 2);     // 2 MB
    ushort*   wv = (ushort*)take((size_t)Dd * Cc * 2);
    ushort*   wr = (ushort*)take((size_t)Dd * Cc * 2);
    ushort*   wo = (ushort*)take((size_t)Cc * Dd * 2);
    float*    pa = (float*)take((size_t)Bb * NCH * Dd * 4); // 1 MB
    float*    pb = (float*)take((size_t)Bb * NCH * Dd * 4);
    float*    sa = (float*)take((size_t)Bb * NCH * Dd * 4);
    float*    sbst = (float*)take((size_t)Bb * NCH * Dd * 4);
    ushort*   rw = xb;

    const int prep_grid = Mm * Cc / 8 / 256;
    dim3 g1(Mm / 128, Dd / 128);
    dim3 g2(Mm / 128, Cc / 128);
    const int wkv_grid = (Bb * NCH * Dd) / 256;   // 1024

    cvt_w<<<4096, 256, 0, stream>>>(Wk, Wv, Wr, Wo, wk, wv, wr, wo);

    prep_mix<<<prep_grid, 256, 0, stream>>>(x, mk, xb);
    gemm_nt<3><<<g1, 256, 0, stream>>>(xb, wk, kb, Dd, Cc);

    prep_mix<<<prep_grid, 256, 0, stream>>>(x, mv, xb);
    gemm_nt<1><<<g1, 256, 0, stream>>>(xb, wv, vb, Dd, Cc);

    prep_mix<<<prep_grid, 256, 0, stream>>>(x, mr, xb);
    gemm_nt<2><<<g1, 256, 0, stream>>>(xb, wr, sb, Dd, Cc);

    wkv_part  <<<wkv_grid, 256, 0, stream>>>(kb, vb, td, pa, pb);
    wkv_prefix<<<(Bb * Dd) / 256, 256, 0, stream>>>(pa, pb, td, sa, sbst);
    wkv_chunk <<<wkv_grid, 256, 0, stream>>>(kb, vb, sb, td, tf, sa, sbst, rw);

    gemm_nt<0><<<g2, 256, 0, stream>>>(rw, wo, out, Cc, Dd);
}

// Round 5
// 421.727 us; speedup vs baseline: 1.6609x; 1.0518x over previous
//
#include <hip/hip_runtime.h>
#include <cstdint>
#include <cstddef>

// Problem constants
#define Bb 8
#define Tt 2048
#define Cc 1024
#define Dd 1024
#define Mm (Bb*Tt)   // 16384 rows
#define CL 64        // wkv chunk length
#define NCH (Tt/CL)  // 32 chunks

// NOTES:
// - inputs/outputs fp32 (round-2 bf16 hypothesis disproved by NaN signature).
// - keep d_ws usage <= 160 MB (160 proven safe, 344 aborted). Now 140 MB.
// - ROUND 4: wkv 3-pass parallel scan (318us -> off the top-5).
// - ROUND 5: (a) LDS XOR swizzle in gemm (4.19M bank-conflict cycles/dispatch,
//   8-way on b128 reads, was the k-loop critical path); (b) single fused
//   prep_mix3 (x read once instead of 3x) via buffer aliasing.

typedef __bf16  bf16x8  __attribute__((ext_vector_type(8)));
typedef float   floatx4 __attribute__((ext_vector_type(4)));

__device__ __forceinline__ ushort f2bf(float f) {
    unsigned u = __float_as_uint(f);
    u = (u + 0x7FFF + ((u >> 16) & 1)) >> 16;   // RNE
    return (ushort)u;
}
__device__ __forceinline__ float bf2f(ushort u) {
    return __uint_as_float(((unsigned)u) << 16);
}

__device__ __forceinline__ void load_lds16(const void* g, void* l) {
    __builtin_amdgcn_global_load_lds((__attribute__((address_space(1))) void*)(g),
                                     (__attribute__((address_space(3))) void*)(l),
                                     16, 0, 0);
}

// ---------------- fused mix + time-shift: fp32 x -> bf16 xk,xv,xr ----------------
__global__ __launch_bounds__(256) void prep_mix3(
        const float* __restrict__ x,
        const float* __restrict__ mk, const float* __restrict__ mv,
        const float* __restrict__ mr,
        ushort* __restrict__ xk, ushort* __restrict__ xv, ushort* __restrict__ xr) {
    int i  = blockIdx.x * 256 + threadIdx.x;     // vec8 chunk id, Mm*Cc/8 total
    int cq = i & (Cc / 8 - 1);                   // 128 vec8 per row
    int m  = i >> 7;
    int t  = m & (Tt - 1);
    float xc[8], xp[8];
    *(float4*)&xc[0] = ((const float4*)x)[i * 2];
    *(float4*)&xc[4] = ((const float4*)x)[i * 2 + 1];
    if (t != 0) {
        *(float4*)&xp[0] = ((const float4*)x)[(i - Cc / 8) * 2];
        *(float4*)&xp[4] = ((const float4*)x)[(i - Cc / 8) * 2 + 1];
    } else {
#pragma unroll
        for (int j = 0; j < 8; j++) xp[j] = 0.f;
    }
    float wk[8], wv[8], wr[8];
    *(float4*)&wk[0] = ((const float4*)mk)[cq * 2];
    *(float4*)&wk[4] = ((const float4*)mk)[cq * 2 + 1];
    *(float4*)&wv[0] = ((const float4*)mv)[cq * 2];
    *(float4*)&wv[4] = ((const float4*)mv)[cq * 2 + 1];
    *(float4*)&wr[0] = ((const float4*)mr)[cq * 2];
    *(float4*)&wr[4] = ((const float4*)mr)[cq * 2 + 1];
    ushort ok[8], ov[8], orr[8];
#pragma unroll
    for (int j = 0; j < 8; j++) {
        float d = xc[j] - xp[j];
        ok[j]  = f2bf(xp[j] + d * wk[j]);
        ov[j]  = f2bf(xp[j] + d * wv[j]);
        orr[j] = f2bf(xp[j] + d * wr[j]);
    }
    ((ulonglong2*)xk)[i] = *(const ulonglong2*)ok;
    ((ulonglong2*)xv)[i] = *(const ulonglong2*)ov;
    ((ulonglong2*)xr)[i] = *(const ulonglong2*)orr;
}

// ---------------- fp32 -> bf16 for the 4 weight matrices ----------------
__global__ __launch_bounds__(256) void cvt_w(
        const float* __restrict__ wk, const float* __restrict__ wv,
        const float* __restrict__ wr, const float* __restrict__ wo,
        ushort* __restrict__ ok, ushort* __restrict__ ov,
        ushort* __restrict__ orr, ushort* __restrict__ oo) {
    int i = blockIdx.x * 256 + threadIdx.x;       // vec4 units, 4 * 2^18 total
    int sel = i >> 18;
    int j = i & ((1 << 18) - 1);
    const float* s = sel == 0 ? wk : sel == 1 ? wv : sel == 2 ? wr : wo;
    ushort* d      = sel == 0 ? ok : sel == 1 ? ov : sel == 2 ? orr : oo;
    float4 f = ((const float4*)s)[j];
    ushort4 o;
    o.x = f2bf(f.x); o.y = f2bf(f.y); o.z = f2bf(f.z); o.w = f2bf(f.w);
    ((ushort4*)d)[j] = o;
}

// ---------------- NT GEMM: Co[m,n] = sum_k A[m,k] * Bw[n,k] ----------------
// 128x128 tile, BK=32, 4 waves x (4x4) 16x16x32 bf16 MFMA (m97 structure).
// LDS XOR swizzle: staging thread t loads global part (t&3)^((t>>3)&3) so
// LDS slot s of row r holds part s^((r>>1)&3); reads use quad^((fr>>1)&3).
// This takes the b128 read pattern from 8-way bank conflict to <=2-way (free).
// MODE: 0 = fp32 out, 1 = bf16 out, 2 = bf16 out + sigmoid, 3 = fp16 out
template<int MODE>
__global__ __launch_bounds__(256) void gemm_nt(
        const ushort* __restrict__ A, const ushort* __restrict__ Bw,
        void* __restrict__ Co, int Ndim, int Kdim) {
    __shared__ __attribute__((aligned(16))) __bf16 As[128 * 32];
    __shared__ __attribute__((aligned(16))) __bf16 Bs[128 * 32];
    const int tid  = threadIdx.x;
    const int lane = tid & 63;
    const int quad = lane >> 4;
    const int fr   = lane & 15;
    const int wave = tid >> 6;
    const int wm   = (wave >> 1) * 64;
    const int wn   = (wave & 1) * 64;
    const long tm  = (long)blockIdx.x * 128;
    const long tn  = (long)blockIdx.y * 128;

    // staging with XOR swizzle
    const int srow  = tid >> 2;
    const int spart = (tid & 3) ^ ((tid >> 3) & 3);
    const ushort* Ag0 = A + (tm + srow) * (long)Kdim + spart * 8;
    const ushort* Ag1 = Ag0 + 64 * (long)Kdim;
    const ushort* Bg0 = Bw + (tn + srow) * (long)Kdim + spart * 8;
    const ushort* Bg1 = Bg0 + 64 * (long)Kdim;
    __bf16* AlA = &As[wave * 512];
    __bf16* AlB = &As[2048 + wave * 512];
    __bf16* BlA = &Bs[wave * 512];
    __bf16* BlB = &Bs[2048 + wave * 512];

    const int swz = (fr >> 1) & 3;    // read-side swizzle selector

    floatx4 zero = {0.f, 0.f, 0.f, 0.f};
    floatx4 acc[4][4];
#pragma unroll
    for (int a1 = 0; a1 < 4; a1++)
#pragma unroll
        for (int b1 = 0; b1 < 4; b1++) acc[a1][b1] = zero;

    for (int kt = 0; kt < Kdim; kt += 32) {
        __syncthreads();
        load_lds16(Ag0 + kt, AlA);
        load_lds16(Ag1 + kt, AlB);
        load_lds16(Bg0 + kt, BlA);
        load_lds16(Bg1 + kt, BlB);
        __syncthreads();

        bf16x8 af[4], bfg[4];
#pragma unroll
        for (int mi = 0; mi < 4; mi++)
            af[mi] = *(const bf16x8*)&As[(wm + mi * 16 + fr) * 32 + (quad ^ swz) * 8];
#pragma unroll
        for (int ni = 0; ni < 4; ni++)
            bfg[ni] = *(const bf16x8*)&Bs[(wn + ni * 16 + fr) * 32 + (quad ^ swz) * 8];
#pragma unroll
        for (int mi = 0; mi < 4; mi++)
#pragma unroll
            for (int ni = 0; ni < 4; ni++)
                acc[mi][ni] = __builtin_amdgcn_mfma_f32_16x16x32_bf16(
                    af[mi], bfg[ni], acc[mi][ni], 0, 0, 0);
    }

#pragma unroll
    for (int mi = 0; mi < 4; mi++)
#pragma unroll
        for (int ni = 0; ni < 4; ni++)
#pragma unroll
            for (int r = 0; r < 4; r++) {
                long grow = tm + wm + mi * 16 + quad * 4 + r;
                long gcol = tn + wn + ni * 16 + fr;
                float v = acc[mi][ni][r];
                if (MODE == 2) v = 1.f / (1.f + __expf(-v));
                if (MODE == 0)      ((float*)Co)[grow * Ndim + gcol] = v;
                else if (MODE == 3) ((_Float16*)Co)[grow * Ndim + gcol] = (_Float16)v;
                else                ((ushort*)Co)[grow * Ndim + gcol] = f2bf(v);
            }
}

// ---------------- WKV: 3-pass chunked parallel scan ----------------
__global__ __launch_bounds__(256) void wkv_part(
        const _Float16* __restrict__ kb, const ushort* __restrict__ vb,
        const float* __restrict__ decay,
        float* __restrict__ pa, float* __restrict__ pb) {
    int gid = blockIdx.x * 256 + threadIdx.x;   // 0..B*NCH*D-1, d fastest
    int d = gid & (Dd - 1);
    int c = (gid >> 10) & (NCH - 1);
    int b = gid >> 15;
    float ew = __expf(-__expf(decay[d]));
    size_t base = ((size_t)b * Tt + (size_t)c * CL) * Dd + d;
    float a = 0.f, bs = 0.f;
    for (int i0 = 0; i0 < CL; i0 += 8) {
        float kr[8], vr[8];
#pragma unroll
        for (int j = 0; j < 8; j++) {
            size_t idx = base + (size_t)(i0 + j) * Dd;
            kr[j] = (float)kb[idx]; vr[j] = bf2f(vb[idx]);
        }
#pragma unroll
        for (int j = 0; j < 8; j++) {
            float ek = __expf(kr[j]);
            a  = ew * a  + ek * vr[j];
            bs = ew * bs + ek;
        }
    }
    int sidx = c * (Bb * Dd) + b * Dd + d;      // [c][b][d]
    pa[sidx] = a; pb[sidx] = bs;
}

__global__ __launch_bounds__(256) void wkv_prefix(
        const float* __restrict__ pa, const float* __restrict__ pb,
        const float* __restrict__ decay,
        float* __restrict__ sa, float* __restrict__ sb) {
    int gid = blockIdx.x * 256 + threadIdx.x;   // 0..B*D-1
    int d = gid & (Dd - 1);
    float ewL = __expf(-__expf(decay[d]) * (float)CL);  // ew^CL, direct
    float ca = 0.f, cb = 0.f;
#pragma unroll
    for (int c = 0; c < NCH; c++) {
        int idx = c * (Bb * Dd) + gid;
        sa[idx] = ca; sb[idx] = cb;
        ca = ewL * ca + pa[idx];
        cb = ewL * cb + pb[idx];
    }
}

__global__ __launch_bounds__(256) void wkv_chunk(
        const _Float16* __restrict__ kb, const ushort* __restrict__ vb,
        const ushort* __restrict__ sr,
        const float* __restrict__ decay, const float* __restrict__ tf,
        const float* __restrict__ sa, const float* __restrict__ sb,
        ushort* __restrict__ rw) {
    int gid = blockIdx.x * 256 + threadIdx.x;
    int d = gid & (Dd - 1);
    int c = (gid >> 10) & (NCH - 1);
    int b = gid >> 15;
    float ew = __expf(-__expf(decay[d]));
    float eu = __expf(tf[d]);
    int sidx = c * (Bb * Dd) + b * Dd + d;
    float a = sa[sidx], bs = sb[sidx];
    size_t base = ((size_t)b * Tt + (size_t)c * CL) * Dd + d;
    for (int i0 = 0; i0 < CL; i0 += 8) {
        float kr[8], vr[8], rr[8];
#pragma unroll
        for (int j = 0; j < 8; j++) {
            size_t idx = base + (size_t)(i0 + j) * Dd;
            kr[j] = (float)kb[idx]; vr[j] = bf2f(vb[idx]); rr[j] = bf2f(sr[idx]);
        }
#pragma unroll
        for (int j = 0; j < 8; j++) {
            float ek  = __expf(kr[j]);
            float ekv = ek * vr[j];
            float out = (eu * ekv + a) / (eu * ek + bs);
            a  = ew * a  + ekv;
            bs = ew * bs + ek;
            rw[base + (size_t)(i0 + j) * Dd] = f2bf(rr[j] * out);
        }
    }
}

extern "C" void kernel_launch(void* const* d_in, const int* in_sizes, int n_in,
                              void* d_out, int out_size, void* d_ws, size_t ws_size,
                              hipStream_t stream) {
    (void)in_sizes; (void)n_in; (void)out_size; (void)ws_size;
    const float* x  = (const float*)d_in[0];
    const float* td = (const float*)d_in[1];
    const float* tf = (const float*)d_in[2];
    const float* mk = (const float*)d_in[3];
    const float* mv = (const float*)d_in[4];
    const float* mr = (const float*)d_in[5];
    const float* Wk = (const float*)d_in[6];
    const float* Wv = (const float*)d_in[7];
    const float* Wr = (const float*)d_in[8];
    const float* Wo = (const float*)d_in[9];
    float* out = (float*)d_out;

    // workspace: 140 MB. Aliasing (sequential-stream safe):
    //   vb <- xk slot (xk dead after gemm-k), sb <- xv slot, rw <- xr slot.
    char* p = (char*)d_ws;
    auto take = [&](size_t n) { char* r = p; p += n; return r; };
    ushort*   xk = (ushort*)take((size_t)Mm * Cc * 2);     // 32 MB, then vb
    ushort*   xv = (ushort*)take((size_t)Mm * Cc * 2);     // 32 MB, then sb
    ushort*   xr = (ushort*)take((size_t)Mm * Cc * 2);     // 32 MB, then rw
    _Float16* kb = (_Float16*)take((size_t)Mm * Dd * 2);   // 32 MB
    ushort*   wk = (ushort*)take((size_t)Dd * Cc * 2);     // 2 MB
    ushort*   wv = (ushort*)take((size_t)Dd * Cc * 2);
    ushort*   wr = (ushort*)take((size_t)Dd * Cc * 2);
    ushort*   wo = (ushort*)take((size_t)Cc * Dd * 2);
    float*    pa = (float*)take((size_t)Bb * NCH * Dd * 4); // 1 MB
    float*    pb = (float*)take((size_t)Bb * NCH * Dd * 4);
    float*    sa = (float*)take((size_t)Bb * NCH * Dd * 4);
    float*    sbst = (float*)take((size_t)Bb * NCH * Dd * 4);
    ushort*   vb = xk;
    ushort*   sb = xv;
    ushort*   rw = xr;

    dim3 g1(Mm / 128, Dd / 128);
    dim3 g2(Mm / 128, Cc / 128);
    const int wkv_grid = (Bb * NCH * Dd) / 256;   // 1024

    cvt_w<<<4096, 256, 0, stream>>>(Wk, Wv, Wr, Wo, wk, wv, wr, wo);
    prep_mix3<<<Mm * Cc / 8 / 256, 256, 0, stream>>>(x, mk, mv, mr, xk, xv, xr);

    gemm_nt<3><<<g1, 256, 0, stream>>>(xk, wk, kb, Dd, Cc);
    gemm_nt<1><<<g1, 256, 0, stream>>>(xv, wv, vb, Dd, Cc);
    gemm_nt<2><<<g1, 256, 0, stream>>>(xr, wr, sb, Dd, Cc);

    wkv_part  <<<wkv_grid, 256, 0, stream>>>(kb, vb, td, pa, pb);
    wkv_prefix<<<(Bb * Dd) / 256, 256, 0, stream>>>(pa, pb, td, sa, sbst);
    wkv_chunk <<<wkv_grid, 256, 0, stream>>>(kb, vb, sb, td, tf, sa, sbst, rw);

    gemm_nt<0><<<g2, 256, 0, stream>>>(rw, wo, out, Cc, Dd);
}

// Round 6
// 407.976 us; speedup vs baseline: 1.7169x; 1.0337x over previous
//
#include <hip/hip_runtime.h>
#include <cstdint>
#include <cstddef>

// Problem constants
#define Bb 8
#define Tt 2048
#define Cc 1024
#define Dd 1024
#define Mm (Bb*Tt)   // 16384 rows
#define CL 64        // wkv chunk length
#define NCH (Tt/CL)  // 32 chunks

// NOTES:
// - inputs/outputs fp32. Keep d_ws <= 160 MB unless ws_size says otherwise
//   (160 proven safe, 344 aborted) -> merged-GEMM path gated on ws_size>=204MB.
// - R4: wkv 3-pass parallel scan (318us -> ~40us total).
// - R5: XOR swizzle killed 4.19M LDS bank conflicts but GEMM unchanged ->
//   conflicts were hidden under exposed HBM latency (~2100 cyc/K-iter).
// - R6: LDS double-buffer (load issue overlaps MFMA phase) + merged 3-proj
//   GEMM dispatch when workspace allows.

typedef __bf16  bf16x8  __attribute__((ext_vector_type(8)));
typedef float   floatx4 __attribute__((ext_vector_type(4)));

__device__ __forceinline__ ushort f2bf(float f) {
    unsigned u = __float_as_uint(f);
    u = (u + 0x7FFF + ((u >> 16) & 1)) >> 16;   // RNE
    return (ushort)u;
}
__device__ __forceinline__ float bf2f(ushort u) {
    return __uint_as_float(((unsigned)u) << 16);
}

__device__ __forceinline__ void load_lds16(const void* g, void* l) {
    __builtin_amdgcn_global_load_lds((__attribute__((address_space(1))) void*)(g),
                                     (__attribute__((address_space(3))) void*)(l),
                                     16, 0, 0);
}

// ---------------- fused mix + time-shift: fp32 x -> bf16 xk,xv,xr ----------------
__global__ __launch_bounds__(256) void prep_mix3(
        const float* __restrict__ x,
        const float* __restrict__ mk, const float* __restrict__ mv,
        const float* __restrict__ mr,
        ushort* __restrict__ xk, ushort* __restrict__ xv, ushort* __restrict__ xr) {
    int i  = blockIdx.x * 256 + threadIdx.x;     // vec8 chunk id, Mm*Cc/8 total
    int cq = i & (Cc / 8 - 1);                   // 128 vec8 per row
    int m  = i >> 7;
    int t  = m & (Tt - 1);
    float xc[8], xp[8];
    *(float4*)&xc[0] = ((const float4*)x)[i * 2];
    *(float4*)&xc[4] = ((const float4*)x)[i * 2 + 1];
    if (t != 0) {
        *(float4*)&xp[0] = ((const float4*)x)[(i - Cc / 8) * 2];
        *(float4*)&xp[4] = ((const float4*)x)[(i - Cc / 8) * 2 + 1];
    } else {
#pragma unroll
        for (int j = 0; j < 8; j++) xp[j] = 0.f;
    }
    float wk[8], wv[8], wr[8];
    *(float4*)&wk[0] = ((const float4*)mk)[cq * 2];
    *(float4*)&wk[4] = ((const float4*)mk)[cq * 2 + 1];
    *(float4*)&wv[0] = ((const float4*)mv)[cq * 2];
    *(float4*)&wv[4] = ((const float4*)mv)[cq * 2 + 1];
    *(float4*)&wr[0] = ((const float4*)mr)[cq * 2];
    *(float4*)&wr[4] = ((const float4*)mr)[cq * 2 + 1];
    ushort ok[8], ov[8], orr[8];
#pragma unroll
    for (int j = 0; j < 8; j++) {
        float d = xc[j] - xp[j];
        ok[j]  = f2bf(xp[j] + d * wk[j]);
        ov[j]  = f2bf(xp[j] + d * wv[j]);
        orr[j] = f2bf(xp[j] + d * wr[j]);
    }
    ((ulonglong2*)xk)[i] = *(const ulonglong2*)ok;
    ((ulonglong2*)xv)[i] = *(const ulonglong2*)ov;
    ((ulonglong2*)xr)[i] = *(const ulonglong2*)orr;
}

// ---------------- fp32 -> bf16 for the 4 weight matrices ----------------
__global__ __launch_bounds__(256) void cvt_w(
        const float* __restrict__ wk, const float* __restrict__ wv,
        const float* __restrict__ wr, const float* __restrict__ wo,
        ushort* __restrict__ ok, ushort* __restrict__ ov,
        ushort* __restrict__ orr, ushort* __restrict__ oo) {
    int i = blockIdx.x * 256 + threadIdx.x;       // vec4 units, 4 * 2^18 total
    int sel = i >> 18;
    int j = i & ((1 << 18) - 1);
    const float* s = sel == 0 ? wk : sel == 1 ? wv : sel == 2 ? wr : wo;
    ushort* d      = sel == 0 ? ok : sel == 1 ? ov : sel == 2 ? orr : oo;
    float4 f = ((const float4*)s)[j];
    ushort4 o;
    o.x = f2bf(f.x); o.y = f2bf(f.y); o.z = f2bf(f.z); o.w = f2bf(f.w);
    ((ushort4*)d)[j] = o;
}

// ======== shared GEMM core (double-buffered LDS, XOR swizzle) ========
// Computes one 128x128 output tile of A(MxK,row) * Bw(NxK,row)^T.
// acc layout per wave: 4x4 grid of 16x16x32 MFMAs over a 64x64 region.
struct GemmCore {
    floatx4 acc[4][4];
    int quad, fr, wave, wm, wn;

    __device__ __forceinline__ void run(
            const ushort* __restrict__ A, const ushort* __restrict__ Bw,
            long tm, long tn, int Kdim,
            __bf16* As, __bf16* Bs) {      // As/Bs: 2 buffers of 128*32 each
        const int tid  = threadIdx.x;
        const int lane = tid & 63;
        quad = lane >> 4;
        fr   = lane & 15;
        wave = tid >> 6;
        wm   = (wave >> 1) * 64;
        wn   = (wave & 1) * 64;

        const int srow  = tid >> 2;
        const int spart = (tid & 3) ^ ((tid >> 3) & 3);   // XOR swizzle (R5)
        const ushort* Ag0 = A + (tm + srow) * (long)Kdim + spart * 8;
        const ushort* Ag1 = Ag0 + 64 * (long)Kdim;
        const ushort* Bg0 = Bw + (tn + srow) * (long)Kdim + spart * 8;
        const ushort* Bg1 = Bg0 + 64 * (long)Kdim;
        const int swz = (fr >> 1) & 3;

        floatx4 zero = {0.f, 0.f, 0.f, 0.f};
#pragma unroll
        for (int a1 = 0; a1 < 4; a1++)
#pragma unroll
            for (int b1 = 0; b1 < 4; b1++) acc[a1][b1] = zero;

        const int niter = Kdim >> 5;
        // prologue: stage iter 0 into buffer 0
        load_lds16(Ag0, &As[wave * 512]);
        load_lds16(Ag1, &As[2048 + wave * 512]);
        load_lds16(Bg0, &Bs[wave * 512]);
        load_lds16(Bg1, &Bs[2048 + wave * 512]);

        for (int it = 0; it < niter; ++it) {
            const int cur = it & 1;
            __bf16* Ac = As + cur * 4096;
            __bf16* Bc = Bs + cur * 4096;
            // barrier drains vmcnt -> buffer `cur` staged; prev reads done
            __syncthreads();
            if (it + 1 < niter) {         // issue next stage BEFORE compute
                const int kt = (it + 1) << 5;
                __bf16* An = As + (cur ^ 1) * 4096;
                __bf16* Bn = Bs + (cur ^ 1) * 4096;
                load_lds16(Ag0 + kt, &An[wave * 512]);
                load_lds16(Ag1 + kt, &An[2048 + wave * 512]);
                load_lds16(Bg0 + kt, &Bn[wave * 512]);
                load_lds16(Bg1 + kt, &Bn[2048 + wave * 512]);
            }
            bf16x8 af[4], bfg[4];
#pragma unroll
            for (int mi = 0; mi < 4; mi++)
                af[mi] = *(const bf16x8*)&Ac[(wm + mi * 16 + fr) * 32 + (quad ^ swz) * 8];
#pragma unroll
            for (int ni = 0; ni < 4; ni++)
                bfg[ni] = *(const bf16x8*)&Bc[(wn + ni * 16 + fr) * 32 + (quad ^ swz) * 8];
#pragma unroll
            for (int mi = 0; mi < 4; mi++)
#pragma unroll
                for (int ni = 0; ni < 4; ni++)
                    acc[mi][ni] = __builtin_amdgcn_mfma_f32_16x16x32_bf16(
                        af[mi], bfg[ni], acc[mi][ni], 0, 0, 0);
        }
    }
};

// ---------------- single GEMM (used for Wo, and serial fallback) ----------------
// MODE: 0 = fp32 out, 1 = bf16 out, 2 = bf16 out + sigmoid, 3 = fp16 out
template<int MODE>
__global__ __launch_bounds__(256) void gemm_nt(
        const ushort* __restrict__ A, const ushort* __restrict__ Bw,
        void* __restrict__ Co, int Ndim, int Kdim) {
    __shared__ __attribute__((aligned(16))) __bf16 As[2 * 128 * 32];
    __shared__ __attribute__((aligned(16))) __bf16 Bs[2 * 128 * 32];
    const long tm = (long)blockIdx.x * 128;
    const long tn = (long)blockIdx.y * 128;
    GemmCore g;
    g.run(A, Bw, tm, tn, Kdim, As, Bs);
#pragma unroll
    for (int mi = 0; mi < 4; mi++)
#pragma unroll
        for (int ni = 0; ni < 4; ni++)
#pragma unroll
            for (int r = 0; r < 4; r++) {
                long grow = tm + g.wm + mi * 16 + g.quad * 4 + r;
                long gcol = tn + g.wn + ni * 16 + g.fr;
                float v = g.acc[mi][ni][r];
                if (MODE == 2) v = 1.f / (1.f + __expf(-v));
                if (MODE == 0)      ((float*)Co)[grow * Ndim + gcol] = v;
                else if (MODE == 3) ((_Float16*)Co)[grow * Ndim + gcol] = (_Float16)v;
                else                ((ushort*)Co)[grow * Ndim + gcol] = f2bf(v);
            }
}

// ---------------- merged 3-projection GEMM (needs ws >= 204 MB) ----------------
// grid (Mm/128, 24): blockIdx.y = proj*8 + ntile. proj 0->kb(fp16),
// 1->vb(bf16), 2->sb(sigmoid bf16).
__global__ __launch_bounds__(256) void gemm3_nt(
        const ushort* __restrict__ xk, const ushort* __restrict__ xv,
        const ushort* __restrict__ xr,
        const ushort* __restrict__ wk, const ushort* __restrict__ wv,
        const ushort* __restrict__ wr,
        _Float16* __restrict__ kb, ushort* __restrict__ vb,
        ushort* __restrict__ sb) {
    __shared__ __attribute__((aligned(16))) __bf16 As[2 * 128 * 32];
    __shared__ __attribute__((aligned(16))) __bf16 Bs[2 * 128 * 32];
    const int proj = blockIdx.y >> 3;
    const long tm = (long)blockIdx.x * 128;
    const long tn = (long)(blockIdx.y & 7) * 128;
    const ushort* A  = proj == 0 ? xk : proj == 1 ? xv : xr;
    const ushort* Bw = proj == 0 ? wk : proj == 1 ? wv : wr;
    GemmCore g;
    g.run(A, Bw, tm, tn, Cc, As, Bs);
#pragma unroll
    for (int mi = 0; mi < 4; mi++)
#pragma unroll
        for (int ni = 0; ni < 4; ni++)
#pragma unroll
            for (int r = 0; r < 4; r++) {
                long grow = tm + g.wm + mi * 16 + g.quad * 4 + r;
                long gcol = tn + g.wn + ni * 16 + g.fr;
                long off = grow * Dd + gcol;
                float v = g.acc[mi][ni][r];
                if (proj == 0)      kb[off] = (_Float16)v;
                else if (proj == 1) vb[off] = f2bf(v);
                else                sb[off] = f2bf(1.f / (1.f + __expf(-v)));
            }
}

// ---------------- WKV: 3-pass chunked parallel scan ----------------
__global__ __launch_bounds__(256) void wkv_part(
        const _Float16* __restrict__ kb, const ushort* __restrict__ vb,
        const float* __restrict__ decay,
        float* __restrict__ pa, float* __restrict__ pb) {
    int gid = blockIdx.x * 256 + threadIdx.x;   // 0..B*NCH*D-1, d fastest
    int d = gid & (Dd - 1);
    int c = (gid >> 10) & (NCH - 1);
    int b = gid >> 15;
    float ew = __expf(-__expf(decay[d]));
    size_t base = ((size_t)b * Tt + (size_t)c * CL) * Dd + d;
    float a = 0.f, bs = 0.f;
    for (int i0 = 0; i0 < CL; i0 += 8) {
        float kr[8], vr[8];
#pragma unroll
        for (int j = 0; j < 8; j++) {
            size_t idx = base + (size_t)(i0 + j) * Dd;
            kr[j] = (float)kb[idx]; vr[j] = bf2f(vb[idx]);
        }
#pragma unroll
        for (int j = 0; j < 8; j++) {
            float ek = __expf(kr[j]);
            a  = ew * a  + ek * vr[j];
            bs = ew * bs + ek;
        }
    }
    int sidx = c * (Bb * Dd) + b * Dd + d;      // [c][b][d]
    pa[sidx] = a; pb[sidx] = bs;
}

__global__ __launch_bounds__(256) void wkv_prefix(
        const float* __restrict__ pa, const float* __restrict__ pb,
        const float* __restrict__ decay,
        float* __restrict__ sa, float* __restrict__ sb) {
    int gid = blockIdx.x * 256 + threadIdx.x;   // 0..B*D-1
    int d = gid & (Dd - 1);
    float ewL = __expf(-__expf(decay[d]) * (float)CL);  // ew^CL, direct
    float ca = 0.f, cb = 0.f;
#pragma unroll
    for (int c = 0; c < NCH; c++) {
        int idx = c * (Bb * Dd) + gid;
        sa[idx] = ca; sb[idx] = cb;
        ca = ewL * ca + pa[idx];
        cb = ewL * cb + pb[idx];
    }
}

__global__ __launch_bounds__(256) void wkv_chunk(
        const _Float16* __restrict__ kb, const ushort* __restrict__ vb,
        const ushort* __restrict__ sr,
        const float* __restrict__ decay, const float* __restrict__ tf,
        const float* __restrict__ sa, const float* __restrict__ sb,
        ushort* __restrict__ rw) {
    int gid = blockIdx.x * 256 + threadIdx.x;
    int d = gid & (Dd - 1);
    int c = (gid >> 10) & (NCH - 1);
    int b = gid >> 15;
    float ew = __expf(-__expf(decay[d]));
    float eu = __expf(tf[d]);
    int sidx = c * (Bb * Dd) + b * Dd + d;
    float a = sa[sidx], bs = sb[sidx];
    size_t base = ((size_t)b * Tt + (size_t)c * CL) * Dd + d;
    for (int i0 = 0; i0 < CL; i0 += 8) {
        float kr[8], vr[8], rr[8];
#pragma unroll
        for (int j = 0; j < 8; j++) {
            size_t idx = base + (size_t)(i0 + j) * Dd;
            kr[j] = (float)kb[idx]; vr[j] = bf2f(vb[idx]); rr[j] = bf2f(sr[idx]);
        }
#pragma unroll
        for (int j = 0; j < 8; j++) {
            float ek  = __expf(kr[j]);
            float ekv = ek * vr[j];
            float out = (eu * ekv + a) / (eu * ek + bs);
            a  = ew * a  + ekv;
            bs = ew * bs + ek;
            rw[base + (size_t)(i0 + j) * Dd] = f2bf(rr[j] * out);
        }
    }
}

extern "C" void kernel_launch(void* const* d_in, const int* in_sizes, int n_in,
                              void* d_out, int out_size, void* d_ws, size_t ws_size,
                              hipStream_t stream) {
    (void)in_sizes; (void)n_in; (void)out_size;
    const float* x  = (const float*)d_in[0];
    const float* td = (const float*)d_in[1];
    const float* tf = (const float*)d_in[2];
    const float* mk = (const float*)d_in[3];
    const float* mv = (const float*)d_in[4];
    const float* mr = (const float*)d_in[5];
    const float* Wk = (const float*)d_in[6];
    const float* Wv = (const float*)d_in[7];
    const float* Wr = (const float*)d_in[8];
    const float* Wo = (const float*)d_in[9];
    float* out = (float*)d_out;

    const size_t xsz = (size_t)Mm * Cc * 2;           // 32 MB
    const size_t wsz = (size_t)Dd * Cc * 2;           // 2 MB
    const size_t ssz = (size_t)Bb * NCH * Dd * 4;     // 1 MB
    const size_t need_merged = 6 * xsz + 4 * wsz + 4 * ssz;   // ~204 MB

    char* p = (char*)d_ws;
    auto take = [&](size_t n) { char* r = p; p += n; return r; };
    ushort*   xk = (ushort*)take(xsz);
    ushort*   xv = (ushort*)take(xsz);
    ushort*   xr = (ushort*)take(xsz);
    _Float16* kb = (_Float16*)take(xsz);
    const bool merged = ws_size >= need_merged;
    ushort *vb, *sb, *rw;
    if (merged) {
        vb = (ushort*)take(xsz);
        sb = (ushort*)take(xsz);
        rw = xk;                       // xk dead after gemm3
    } else {
        vb = xk;                       // serial aliasing (R5 layout)
        sb = xv;
        rw = xr;
    }
    ushort* wk = (ushort*)take(wsz);
    ushort* wv = (ushort*)take(wsz);
    ushort* wr = (ushort*)take(wsz);
    ushort* wo = (ushort*)take(wsz);
    float*  pa = (float*)take(ssz);
    float*  pb = (float*)take(ssz);
    float*  sa = (float*)take(ssz);
    float*  sbst = (float*)take(ssz);

    dim3 g1(Mm / 128, Dd / 128);
    dim3 g2(Mm / 128, Cc / 128);
    dim3 g3(Mm / 128, 3 * Dd / 128);
    const int wkv_grid = (Bb * NCH * Dd) / 256;   // 1024

    cvt_w<<<4096, 256, 0, stream>>>(Wk, Wv, Wr, Wo, wk, wv, wr, wo);
    prep_mix3<<<Mm * Cc / 8 / 256, 256, 0, stream>>>(x, mk, mv, mr, xk, xv, xr);

    if (merged) {
        gemm3_nt<<<g3, 256, 0, stream>>>(xk, xv, xr, wk, wv, wr, kb, vb, sb);
    } else {
        gemm_nt<3><<<g1, 256, 0, stream>>>(xk, wk, kb, Dd, Cc);
        gemm_nt<1><<<g1, 256, 0, stream>>>(xv, wv, vb, Dd, Cc);
        gemm_nt<2><<<g1, 256, 0, stream>>>(xr, wr, sb, Dd, Cc);
    }

    wkv_part  <<<wkv_grid, 256, 0, stream>>>(kb, vb, td, pa, pb);
    wkv_prefix<<<(Bb * Dd) / 256, 256, 0, stream>>>(pa, pb, td, sa, sbst);
    wkv_chunk <<<wkv_grid, 256, 0, stream>>>(kb, vb, sb, td, tf, sa, sbst, rw);

    gemm_nt<0><<<g2, 256, 0, stream>>>(rw, wo, out, Cc, Dd);
}